// Round 1
// baseline (2566.974 us; speedup 1.0000x reference)
//
#include <hip/hip_runtime.h>

// MoE block: B=4,S=2048 -> T=8192 tokens, D=2048, F=8192, E=8, K=2
#define T_TOK 8192
#define DIM   2048
#define FFN   8192
#define NE    8
#define TOPK  2

typedef unsigned short ushort_t;
typedef unsigned short ushort8  __attribute__((ext_vector_type(8)));
typedef unsigned short ushort4v __attribute__((ext_vector_type(4)));
typedef short bf16x8 __attribute__((ext_vector_type(8)));
typedef float f32x4  __attribute__((ext_vector_type(4)));

__device__ __forceinline__ ushort_t f2bf(float f) {
  unsigned int u = __float_as_uint(f);
  u += 0x7FFFu + ((u >> 16) & 1u);   // RNE
  return (ushort_t)(u >> 16);
}
__device__ __forceinline__ float bf2f(ushort_t u) {
  return __uint_as_float(((unsigned int)u) << 16);
}

// ---------------- cast x -> bf16 ----------------
__global__ void k_cast(const float* __restrict__ x, ushort_t* __restrict__ xbf) {
  int i = blockIdx.x * blockDim.x + threadIdx.x;     // 4 elems / thread
  float4 v = reinterpret_cast<const float4*>(x)[i];
  ushort4v o;
  o.x = f2bf(v.x); o.y = f2bf(v.y); o.z = f2bf(v.z); o.w = f2bf(v.w);
  reinterpret_cast<ushort4v*>(xbf)[i] = o;
}

// ---------------- router: logits fp32, top2 + softmax ----------------
__global__ __launch_bounds__(256) void k_router(
    const float* __restrict__ x, const float* __restrict__ rw,
    int* __restrict__ tidx, float* __restrict__ twt, int* __restrict__ counts) {
  int t = blockIdx.x;
  int tid = threadIdx.x;
  int lane = tid & 63, wave = tid >> 6;
  float acc[NE];
#pragma unroll
  for (int e = 0; e < NE; e++) acc[e] = 0.f;
  const float* xr = x + (size_t)t * DIM;
  for (int d = tid; d < DIM; d += 256) {
    float xv = xr[d];
    const float* r = rw + d * NE;
#pragma unroll
    for (int e = 0; e < NE; e++) acc[e] += xv * r[e];
  }
  __shared__ float wsum[4][NE];
#pragma unroll
  for (int e = 0; e < NE; e++) {
    float v = acc[e];
#pragma unroll
    for (int off = 32; off > 0; off >>= 1) v += __shfl_down(v, off);
    if (lane == 0) wsum[wave][e] = v;
  }
  __syncthreads();
  if (tid == 0) {
    float lg[NE];
#pragma unroll
    for (int e = 0; e < NE; e++) lg[e] = wsum[0][e] + wsum[1][e] + wsum[2][e] + wsum[3][e];
    int i0 = 0; float v0 = lg[0];
#pragma unroll
    for (int e = 1; e < NE; e++) if (lg[e] > v0) { v0 = lg[e]; i0 = e; }
    int i1 = -1; float v1 = -3.4e38f;
#pragma unroll
    for (int e = 0; e < NE; e++) if (e != i0 && lg[e] > v1) { v1 = lg[e]; i1 = e; }
    float e1 = expf(v1 - v0);
    float s = 1.f + e1;
    tidx[t * 2 + 0] = i0; tidx[t * 2 + 1] = i1;
    twt[t * 2 + 0] = 1.f / s; twt[t * 2 + 1] = e1 / s;
    atomicAdd(&counts[i0], 1);
    atomicAdd(&counts[i1], 1);
  }
}

// ---------------- offsets = exclusive scan of counts ----------------
__global__ void k_scan(const int* __restrict__ counts, int* __restrict__ offsets) {
  if (threadIdx.x == 0) {
    int s = 0;
    for (int e = 0; e < NE; e++) { offsets[e] = s; s += counts[e]; }
    offsets[NE] = s;
  }
}

// ---------------- fill per-expert token lists ----------------
__global__ void k_fill(const int* __restrict__ tidx, const float* __restrict__ twt,
                       const int* __restrict__ offsets, int* __restrict__ cursors,
                       int* __restrict__ ltok, float* __restrict__ lwt, int* __restrict__ ppos) {
  int t = blockIdx.x * blockDim.x + threadIdx.x;
  if (t >= T_TOK) return;
#pragma unroll
  for (int k = 0; k < TOPK; k++) {
    int e = tidx[t * 2 + k];
    int pos = atomicAdd(&cursors[e], 1);
    int p = offsets[e] + pos;
    ltok[p] = t;
    lwt[p] = twt[t * 2 + k];
    ppos[t * 2 + k] = p;
  }
}

// ---------------- GEMM tiles ----------------
#define BM 128
#define BN 128
#define BK 32
#define LDT (BK + 8)   // +16B pad per row: breaks the 64B-stride bank alias

// GEMM1: H[p,f] = gelu( gather(x)[p,:] @ w1[e] + b1[e] )   (bf16 out)
__global__ __launch_bounds__(256) void k_gemm1(
    const ushort_t* __restrict__ xbf, const float* __restrict__ w1, const float* __restrict__ b1,
    const int* __restrict__ counts, const int* __restrict__ offsets,
    const int* __restrict__ ltok, ushort_t* __restrict__ H) {
  int e = blockIdx.z;
  int cnt = counts[e];
  int row0 = blockIdx.y * BM;
  if (row0 >= cnt) return;
  int base = offsets[e];
  int col0 = blockIdx.x * BN;
  const float* W = w1 + (size_t)e * DIM * FFN;

  __shared__ __align__(16) ushort_t As[BM][LDT];
  __shared__ __align__(16) ushort_t Bs[BN][LDT];

  int tid = threadIdx.x;
  int wave = tid >> 6, lane = tid & 63;
  int wm = wave >> 1, wn = wave & 1;     // 2x2 waves of 64x64
  int lm = lane & 15, lg = lane >> 4;

  int ar = tid >> 1;                      // A staging: row 0..127
  int ak = (tid & 1) * 16;                // k segment 0 / 16
  int arow = min(row0 + ar, cnt - 1);
  const ushort_t* xsrc = xbf + (size_t)ltok[base + arow] * DIM;

  int bn = tid & 127;                     // B staging: col within tile
  int bkk = (tid >> 7) * 16;              // k segment 0 / 16

  f32x4 acc[4][4];
#pragma unroll
  for (int m = 0; m < 4; m++)
#pragma unroll
    for (int n = 0; n < 4; n++) acc[m][n] = (f32x4){0.f, 0.f, 0.f, 0.f};

  for (int k0 = 0; k0 < DIM; k0 += BK) {
    ushort8 a0 = *reinterpret_cast<const ushort8*>(xsrc + k0 + ak);
    ushort8 a1 = *reinterpret_cast<const ushort8*>(xsrc + k0 + ak + 8);
    const float* Wp = W + (size_t)(k0 + bkk) * FFN + (col0 + bn);
    float bv[16];
#pragma unroll
    for (int i = 0; i < 16; i++) bv[i] = Wp[(size_t)i * FFN];   // coalesced across lanes
    __syncthreads();
    *reinterpret_cast<ushort8*>(&As[ar][ak]) = a0;
    *reinterpret_cast<ushort8*>(&As[ar][ak + 8]) = a1;
    ushort8 p0, p1;
#pragma unroll
    for (int i = 0; i < 8; i++) { p0[i] = f2bf(bv[i]); p1[i] = f2bf(bv[i + 8]); }
    *reinterpret_cast<ushort8*>(&Bs[bn][bkk]) = p0;      // transposed: Bs[n][k]
    *reinterpret_cast<ushort8*>(&Bs[bn][bkk + 8]) = p1;
    __syncthreads();
    bf16x8 af[4], bfr[4];
#pragma unroll
    for (int m = 0; m < 4; m++)
      af[m] = *reinterpret_cast<const bf16x8*>(&As[wm * 64 + m * 16 + lm][lg * 8]);
#pragma unroll
    for (int n = 0; n < 4; n++)
      bfr[n] = *reinterpret_cast<const bf16x8*>(&Bs[wn * 64 + n * 16 + lm][lg * 8]);
#pragma unroll
    for (int m = 0; m < 4; m++)
#pragma unroll
      for (int n = 0; n < 4; n++)
        acc[m][n] = __builtin_amdgcn_mfma_f32_16x16x32_bf16(af[m], bfr[n], acc[m][n], 0, 0, 0);
  }
#pragma unroll
  for (int m = 0; m < 4; m++) {
#pragma unroll
    for (int n = 0; n < 4; n++) {
      int f = col0 + wn * 64 + n * 16 + lm;
      float bias = b1[e * FFN + f];
#pragma unroll
      for (int r = 0; r < 4; r++) {
        int row = row0 + wm * 64 + m * 16 + lg * 4 + r;
        if (row < cnt) {
          float v = acc[m][n][r] + bias;
          float g = 0.5f * v * (1.0f + erff(v * 0.70710678118654752f)); // exact gelu
          H[(size_t)(base + row) * FFN + f] = f2bf(g);
        }
      }
    }
  }
}

// GEMM2: contrib[p,d] = cw[p] * ( H[p,:] @ w2[e] + b2[e] )   (bf16 out)
__global__ __launch_bounds__(256) void k_gemm2(
    const ushort_t* __restrict__ H, const float* __restrict__ w2, const float* __restrict__ b2,
    const int* __restrict__ counts, const int* __restrict__ offsets,
    const float* __restrict__ lwt, ushort_t* __restrict__ contrib) {
  int e = blockIdx.z;
  int cnt = counts[e];
  int row0 = blockIdx.y * BM;
  if (row0 >= cnt) return;
  int base = offsets[e];
  int col0 = blockIdx.x * BN;
  const float* W = w2 + (size_t)e * FFN * DIM;

  __shared__ __align__(16) ushort_t As[BM][LDT];
  __shared__ __align__(16) ushort_t Bs[BN][LDT];

  int tid = threadIdx.x;
  int wave = tid >> 6, lane = tid & 63;
  int wm = wave >> 1, wn = wave & 1;
  int lm = lane & 15, lg = lane >> 4;

  int ar = tid >> 1;
  int ak = (tid & 1) * 16;
  int arow = min(row0 + ar, cnt - 1);
  const ushort_t* asrc = H + (size_t)(base + arow) * FFN;

  int bn = tid & 127;
  int bkk = (tid >> 7) * 16;

  f32x4 acc[4][4];
#pragma unroll
  for (int m = 0; m < 4; m++)
#pragma unroll
    for (int n = 0; n < 4; n++) acc[m][n] = (f32x4){0.f, 0.f, 0.f, 0.f};

  for (int k0 = 0; k0 < FFN; k0 += BK) {
    ushort8 a0 = *reinterpret_cast<const ushort8*>(asrc + k0 + ak);
    ushort8 a1 = *reinterpret_cast<const ushort8*>(asrc + k0 + ak + 8);
    const float* Wp = W + (size_t)(k0 + bkk) * DIM + (col0 + bn);
    float bv[16];
#pragma unroll
    for (int i = 0; i < 16; i++) bv[i] = Wp[(size_t)i * DIM];
    __syncthreads();
    *reinterpret_cast<ushort8*>(&As[ar][ak]) = a0;
    *reinterpret_cast<ushort8*>(&As[ar][ak + 8]) = a1;
    ushort8 p0, p1;
#pragma unroll
    for (int i = 0; i < 8; i++) { p0[i] = f2bf(bv[i]); p1[i] = f2bf(bv[i + 8]); }
    *reinterpret_cast<ushort8*>(&Bs[bn][bkk]) = p0;
    *reinterpret_cast<ushort8*>(&Bs[bn][bkk + 8]) = p1;
    __syncthreads();
    bf16x8 af[4], bfr[4];
#pragma unroll
    for (int m = 0; m < 4; m++)
      af[m] = *reinterpret_cast<const bf16x8*>(&As[wm * 64 + m * 16 + lm][lg * 8]);
#pragma unroll
    for (int n = 0; n < 4; n++)
      bfr[n] = *reinterpret_cast<const bf16x8*>(&Bs[wn * 64 + n * 16 + lm][lg * 8]);
#pragma unroll
    for (int m = 0; m < 4; m++)
#pragma unroll
      for (int n = 0; n < 4; n++)
        acc[m][n] = __builtin_amdgcn_mfma_f32_16x16x32_bf16(af[m], bfr[n], acc[m][n], 0, 0, 0);
  }
#pragma unroll
  for (int m = 0; m < 4; m++) {
#pragma unroll
    for (int n = 0; n < 4; n++) {
      int d = col0 + wn * 64 + n * 16 + lm;
      float bias = b2[e * DIM + d];
#pragma unroll
      for (int r = 0; r < 4; r++) {
        int row = row0 + wm * 64 + m * 16 + lg * 4 + r;
        if (row < cnt) {
          float v = (acc[m][n][r] + bias) * lwt[base + row];
          contrib[(size_t)(base + row) * DIM + d] = f2bf(v);
        }
      }
    }
  }
}

// ---------------- combine: out = x + contrib[p0] + contrib[p1] ----------------
__global__ void k_combine(const float* __restrict__ x, const ushort_t* __restrict__ contrib,
                          const int* __restrict__ ppos, float* __restrict__ out) {
  int i = blockIdx.x * blockDim.x + threadIdx.x;   // 4 floats / thread
  int t = i / (DIM / 4);
  int dq = i % (DIM / 4);
  int p0 = ppos[t * 2 + 0], p1 = ppos[t * 2 + 1];
  float4 xv = reinterpret_cast<const float4*>(x)[i];
  ushort4v c0 = reinterpret_cast<const ushort4v*>(contrib + (size_t)p0 * DIM)[dq];
  ushort4v c1 = reinterpret_cast<const ushort4v*>(contrib + (size_t)p1 * DIM)[dq];
  float4 o;
  o.x = xv.x + bf2f(c0.x) + bf2f(c1.x);
  o.y = xv.y + bf2f(c0.y) + bf2f(c1.y);
  o.z = xv.z + bf2f(c0.z) + bf2f(c1.z);
  o.w = xv.w + bf2f(c0.w) + bf2f(c1.w);
  reinterpret_cast<float4*>(out)[i] = o;
}

extern "C" void kernel_launch(void* const* d_in, const int* in_sizes, int n_in,
                              void* d_out, int out_size, void* d_ws, size_t ws_size,
                              hipStream_t stream) {
  const float* x  = (const float*)d_in[0];
  const float* rw = (const float*)d_in[1];
  const float* w1 = (const float*)d_in[2];
  const float* b1 = (const float*)d_in[3];
  const float* w2 = (const float*)d_in[4];
  const float* b2 = (const float*)d_in[5];
  float* out = (float*)d_out;
  char* ws = (char*)d_ws;

  const size_t MB = 1u << 20;
  int*   counts  = (int*)(ws);
  int*   offsets = (int*)(ws + 64);
  int*   cursors = (int*)(ws + 128);
  int*   tidx    = (int*)(ws + 1 * MB);
  float* twt     = (float*)(ws + 2 * MB);
  int*   ltok    = (int*)(ws + 3 * MB);
  float* lwt     = (float*)(ws + 4 * MB);
  int*   ppos    = (int*)(ws + 5 * MB);
  ushort_t* xbf     = (ushort_t*)(ws + 6 * MB);     // 32 MB
  ushort_t* contrib = (ushort_t*)(ws + 40 * MB);    // 64 MB
  ushort_t* Hbuf    = (ushort_t*)(ws + 104 * MB);   // 256 MB
  const size_t NEED = 360 * MB;
  if (ws_size < NEED) {  // clean, loud failure instead of OOB writes
    hipMemsetAsync(d_out, 0, (size_t)out_size * sizeof(float), stream);
    return;
  }

  hipMemsetAsync(ws, 0, 256, stream);  // counts + cursors
  k_cast<<<dim3((T_TOK * (size_t)DIM / 4) / 256), 256, 0, stream>>>(x, xbf);
  k_router<<<T_TOK, 256, 0, stream>>>(x, rw, tidx, twt, counts);
  k_scan<<<1, 64, 0, stream>>>(counts, offsets);
  k_fill<<<T_TOK / 256, 256, 0, stream>>>(tidx, twt, offsets, cursors, ltok, lwt, ppos);
  k_gemm1<<<dim3(FFN / BN, T_TOK / BM, NE), 256, 0, stream>>>(xbf, w1, b1, counts, offsets, ltok, Hbuf);
  k_gemm2<<<dim3(DIM / BN, T_TOK / BM, NE), 256, 0, stream>>>(Hbuf, w2, b2, counts, offsets, lwt, contrib);
  k_combine<<<dim3((T_TOK * (size_t)DIM / 4) / 256), 256, 0, stream>>>(x, contrib, ppos, out);
}

// Round 2
// 2193.391 us; speedup vs baseline: 1.1703x; 1.1703x over previous
//
#include <hip/hip_runtime.h>

// MoE block: B=4,S=2048 -> T=8192 tokens, D=2048, F=8192, E=8, K=2
#define T_TOK 8192
#define DIM   2048
#define FFN   8192
#define NE    8
#define TOPK  2

typedef unsigned short ushort_t;
typedef unsigned short ushort8  __attribute__((ext_vector_type(8)));
typedef unsigned short ushort4v __attribute__((ext_vector_type(4)));
typedef short bf16x8 __attribute__((ext_vector_type(8)));
typedef float f32x4  __attribute__((ext_vector_type(4)));

__device__ __forceinline__ ushort_t f2bf(float f) {
  unsigned int u = __float_as_uint(f);
  u += 0x7FFFu + ((u >> 16) & 1u);   // RNE
  return (ushort_t)(u >> 16);
}
__device__ __forceinline__ float bf2f(ushort_t u) {
  return __uint_as_float(((unsigned int)u) << 16);
}

// async global->LDS, 16B per lane. LDS dest must be wave-uniform base; HW adds lane*16.
__device__ __forceinline__ void gload16(const void* g, void* l) {
  __builtin_amdgcn_global_load_lds((const __attribute__((address_space(1))) void*)g,
                                   (__attribute__((address_space(3))) void*)l, 16, 0, 0);
}

// ---------------- cast x -> bf16 ----------------
__global__ void k_cast(const float* __restrict__ x, ushort_t* __restrict__ xbf) {
  int i = blockIdx.x * blockDim.x + threadIdx.x;     // 4 elems / thread
  float4 v = reinterpret_cast<const float4*>(x)[i];
  ushort4v o;
  o.x = f2bf(v.x); o.y = f2bf(v.y); o.z = f2bf(v.z); o.w = f2bf(v.w);
  reinterpret_cast<ushort4v*>(xbf)[i] = o;
}

// ---------------- weight convert+transpose: fp32 [R][C] -> bf16 [C][R] ----------------
#define TT 64
__global__ __launch_bounds__(256) void k_wcvt(const float* __restrict__ in,
                                              ushort_t* __restrict__ outp, int R, int C) {
  __shared__ ushort_t t[TT][TT + 8];   // 144B rows: vector b64 writes ~conflict-free
  int e = blockIdx.z;
  const float* src = in + (size_t)e * R * C;
  ushort_t* dst = outp + (size_t)e * R * C;
  int r0 = blockIdx.y * TT, c0 = blockIdx.x * TT;
  int tid = threadIdx.x;
  int rr = tid >> 4;       // 0..15
  int c4 = tid & 15;       // float4 col group
#pragma unroll
  for (int i = 0; i < 4; i++) {
    int r = rr + i * 16;
    float4 v = *reinterpret_cast<const float4*>(src + (size_t)(r0 + r) * C + c0 + c4 * 4);
    ushort4v p;
    p.x = f2bf(v.x); p.y = f2bf(v.y); p.z = f2bf(v.z); p.w = f2bf(v.w);
    *reinterpret_cast<ushort4v*>(&t[r][c4 * 4]) = p;
  }
  __syncthreads();
  int c = tid >> 2, rs = tid & 3;      // each thread: output row c0+c, 16 r-elems
  ushort_t tmp[16];
#pragma unroll
  for (int i = 0; i < 16; i++) tmp[i] = t[rs * 16 + i][c];
  ushort8 v0, v1;
#pragma unroll
  for (int i = 0; i < 8; i++) { v0[i] = tmp[i]; v1[i] = tmp[8 + i]; }
  ushort_t* drow = dst + (size_t)(c0 + c) * R + r0 + rs * 16;
  *reinterpret_cast<ushort8*>(drow) = v0;
  *reinterpret_cast<ushort8*>(drow + 8) = v1;
}

// ---------------- router: logits fp32, top2 + softmax ----------------
__global__ __launch_bounds__(256) void k_router(
    const float* __restrict__ x, const float* __restrict__ rw,
    int* __restrict__ tidx, float* __restrict__ twt, int* __restrict__ counts) {
  int t = blockIdx.x;
  int tid = threadIdx.x;
  int lane = tid & 63, wave = tid >> 6;
  float acc[NE];
#pragma unroll
  for (int e = 0; e < NE; e++) acc[e] = 0.f;
  const float* xr = x + (size_t)t * DIM;
  for (int d = tid; d < DIM; d += 256) {
    float xv = xr[d];
    const float* r = rw + d * NE;
#pragma unroll
    for (int e = 0; e < NE; e++) acc[e] += xv * r[e];
  }
  __shared__ float wsum[4][NE];
#pragma unroll
  for (int e = 0; e < NE; e++) {
    float v = acc[e];
#pragma unroll
    for (int off = 32; off > 0; off >>= 1) v += __shfl_down(v, off);
    if (lane == 0) wsum[wave][e] = v;
  }
  __syncthreads();
  if (tid == 0) {
    float lg[NE];
#pragma unroll
    for (int e = 0; e < NE; e++) lg[e] = wsum[0][e] + wsum[1][e] + wsum[2][e] + wsum[3][e];
    int i0 = 0; float v0 = lg[0];
#pragma unroll
    for (int e = 1; e < NE; e++) if (lg[e] > v0) { v0 = lg[e]; i0 = e; }
    int i1 = -1; float v1 = -3.4e38f;
#pragma unroll
    for (int e = 0; e < NE; e++) if (e != i0 && lg[e] > v1) { v1 = lg[e]; i1 = e; }
    float e1 = expf(v1 - v0);
    float s = 1.f + e1;
    tidx[t * 2 + 0] = i0; tidx[t * 2 + 1] = i1;
    twt[t * 2 + 0] = 1.f / s; twt[t * 2 + 1] = e1 / s;
    atomicAdd(&counts[i0], 1);
    atomicAdd(&counts[i1], 1);
  }
}

__global__ void k_scan(const int* __restrict__ counts, int* __restrict__ offsets) {
  if (threadIdx.x == 0) {
    int s = 0;
    for (int e = 0; e < NE; e++) { offsets[e] = s; s += counts[e]; }
    offsets[NE] = s;
  }
}

__global__ void k_fill(const int* __restrict__ tidx, const float* __restrict__ twt,
                       const int* __restrict__ offsets, int* __restrict__ cursors,
                       int* __restrict__ ltok, float* __restrict__ lwt, int* __restrict__ ppos) {
  int t = blockIdx.x * blockDim.x + threadIdx.x;
  if (t >= T_TOK) return;
#pragma unroll
  for (int k = 0; k < TOPK; k++) {
    int e = tidx[t * 2 + k];
    int pos = atomicAdd(&cursors[e], 1);
    int p = offsets[e] + pos;
    ltok[p] = t;
    lwt[p] = twt[t * 2 + k];
    ppos[t * 2 + k] = p;
  }
}

// ---------------- m97-style GEMMs: 128x128x32, global_load_lds, linear LDS ----------------
#define BM 128
#define BN 128
#define BK 32

// GEMM1: H[p,f] = gelu( gather(x)[p,:] @ w1t[e]^T + b1[e] )   w1t: [F][D] bf16
__global__ __launch_bounds__(256) void k_gemm1(
    const ushort_t* __restrict__ xbf, const ushort_t* __restrict__ w1t, const float* __restrict__ b1,
    const int* __restrict__ counts, const int* __restrict__ offsets,
    const int* __restrict__ ltok, ushort_t* __restrict__ H) {
  int e = blockIdx.z;
  int cnt = counts[e];
  int row0 = blockIdx.y * BM;
  if (row0 >= cnt) return;
  int base = offsets[e];
  int col0 = blockIdx.x * BN;
  const ushort_t* Bt = w1t + (size_t)e * DIM * FFN;

  __shared__ __align__(16) ushort_t As[BM * BK];   // linear [128][32]
  __shared__ __align__(16) ushort_t Bs[BN * BK];

  int tid = threadIdx.x;
  int wave = tid >> 6, lane = tid & 63;
  int wm = wave >> 1, wn = wave & 1;
  int lm = lane & 15, lg = lane >> 4;

  // staging: flat 16B chunk f = j*256 + tid; LDS row = f/4, k-seg = (f%4)*8 elems
  int srow = tid >> 2, seg = tid & 3;
  const ushort_t* asrc[2]; const ushort_t* bsrc[2];
#pragma unroll
  for (int j = 0; j < 2; j++) {
    int ar = min(row0 + j * 64 + srow, cnt - 1);
    asrc[j] = xbf + (size_t)ltok[base + ar] * DIM + seg * 8;
    bsrc[j] = Bt + (size_t)(col0 + j * 64 + srow) * DIM + seg * 8;
  }
  f32x4 acc[4][4];
#pragma unroll
  for (int m = 0; m < 4; m++)
#pragma unroll
    for (int n = 0; n < 4; n++) acc[m][n] = (f32x4){0.f, 0.f, 0.f, 0.f};

  for (int k0 = 0; k0 < DIM; k0 += BK) {
#pragma unroll
    for (int j = 0; j < 2; j++) {
      gload16(asrc[j] + k0, &As[(j * 256 + wave * 64) * 8]);
      gload16(bsrc[j] + k0, &Bs[(j * 256 + wave * 64) * 8]);
    }
    __syncthreads();   // compiler drains vmcnt before barrier
    bf16x8 af[4], bfv[4];
#pragma unroll
    for (int m = 0; m < 4; m++)
      af[m] = *reinterpret_cast<const bf16x8*>(&As[(wm * 64 + m * 16 + lm) * BK + lg * 8]);
#pragma unroll
    for (int n = 0; n < 4; n++)
      bfv[n] = *reinterpret_cast<const bf16x8*>(&Bs[(wn * 64 + n * 16 + lm) * BK + lg * 8]);
#pragma unroll
    for (int m = 0; m < 4; m++)
#pragma unroll
      for (int n = 0; n < 4; n++)
        acc[m][n] = __builtin_amdgcn_mfma_f32_16x16x32_bf16(af[m], bfv[n], acc[m][n], 0, 0, 0);
    __syncthreads();
  }
#pragma unroll
  for (int m = 0; m < 4; m++) {
#pragma unroll
    for (int n = 0; n < 4; n++) {
      int f = col0 + wn * 64 + n * 16 + lm;
      float bias = b1[e * FFN + f];
#pragma unroll
      for (int r = 0; r < 4; r++) {
        int row = row0 + wm * 64 + m * 16 + lg * 4 + r;
        if (row < cnt) {
          float v = acc[m][n][r] + bias;
          float g = 0.5f * v * (1.0f + erff(v * 0.70710678118654752f)); // exact gelu
          H[(size_t)(base + row) * FFN + f] = f2bf(g);
        }
      }
    }
  }
}

// GEMM2: contrib[p,d] = cw[p] * ( H[p,:] @ w2t[e]^T + b2[e] )   w2t: [D][F] bf16
__global__ __launch_bounds__(256) void k_gemm2(
    const ushort_t* __restrict__ H, const ushort_t* __restrict__ w2t, const float* __restrict__ b2,
    const int* __restrict__ counts, const int* __restrict__ offsets,
    const float* __restrict__ lwt, ushort_t* __restrict__ contrib) {
  int e = blockIdx.z;
  int cnt = counts[e];
  int row0 = blockIdx.y * BM;
  if (row0 >= cnt) return;
  int base = offsets[e];
  int col0 = blockIdx.x * BN;
  const ushort_t* Bt = w2t + (size_t)e * DIM * FFN;

  __shared__ __align__(16) ushort_t As[BM * BK];
  __shared__ __align__(16) ushort_t Bs[BN * BK];

  int tid = threadIdx.x;
  int wave = tid >> 6, lane = tid & 63;
  int wm = wave >> 1, wn = wave & 1;
  int lm = lane & 15, lg = lane >> 4;

  int srow = tid >> 2, seg = tid & 3;
  const ushort_t* asrc[2]; const ushort_t* bsrc[2];
#pragma unroll
  for (int j = 0; j < 2; j++) {
    int ar = min(row0 + j * 64 + srow, cnt - 1);
    asrc[j] = H + (size_t)(base + ar) * FFN + seg * 8;
    bsrc[j] = Bt + (size_t)(col0 + j * 64 + srow) * FFN + seg * 8;
  }
  f32x4 acc[4][4];
#pragma unroll
  for (int m = 0; m < 4; m++)
#pragma unroll
    for (int n = 0; n < 4; n++) acc[m][n] = (f32x4){0.f, 0.f, 0.f, 0.f};

  for (int k0 = 0; k0 < FFN; k0 += BK) {
#pragma unroll
    for (int j = 0; j < 2; j++) {
      gload16(asrc[j] + k0, &As[(j * 256 + wave * 64) * 8]);
      gload16(bsrc[j] + k0, &Bs[(j * 256 + wave * 64) * 8]);
    }
    __syncthreads();
    bf16x8 af[4], bfv[4];
#pragma unroll
    for (int m = 0; m < 4; m++)
      af[m] = *reinterpret_cast<const bf16x8*>(&As[(wm * 64 + m * 16 + lm) * BK + lg * 8]);
#pragma unroll
    for (int n = 0; n < 4; n++)
      bfv[n] = *reinterpret_cast<const bf16x8*>(&Bs[(wn * 64 + n * 16 + lm) * BK + lg * 8]);
#pragma unroll
    for (int m = 0; m < 4; m++)
#pragma unroll
      for (int n = 0; n < 4; n++)
        acc[m][n] = __builtin_amdgcn_mfma_f32_16x16x32_bf16(af[m], bfv[n], acc[m][n], 0, 0, 0);
    __syncthreads();
  }
#pragma unroll
  for (int m = 0; m < 4; m++) {
#pragma unroll
    for (int n = 0; n < 4; n++) {
      int d = col0 + wn * 64 + n * 16 + lm;
      float bias = b2[e * DIM + d];
#pragma unroll
      for (int r = 0; r < 4; r++) {
        int row = row0 + wm * 64 + m * 16 + lg * 4 + r;
        if (row < cnt) {
          float v = (acc[m][n][r] + bias) * lwt[base + row];
          contrib[(size_t)(base + row) * DIM + d] = f2bf(v);
        }
      }
    }
  }
}

// ---------------- combine: out = x + contrib[p0] + contrib[p1] ----------------
__global__ void k_combine(const float* __restrict__ x, const ushort_t* __restrict__ contrib,
                          const int* __restrict__ ppos, float* __restrict__ out) {
  int i = blockIdx.x * blockDim.x + threadIdx.x;   // 4 floats / thread
  int t = i / (DIM / 4);
  int dq = i % (DIM / 4);
  int p0 = ppos[t * 2 + 0], p1 = ppos[t * 2 + 1];
  float4 xv = reinterpret_cast<const float4*>(x)[i];
  ushort4v c0 = reinterpret_cast<const ushort4v*>(contrib + (size_t)p0 * DIM)[dq];
  ushort4v c1 = reinterpret_cast<const ushort4v*>(contrib + (size_t)p1 * DIM)[dq];
  float4 o;
  o.x = xv.x + bf2f(c0.x) + bf2f(c1.x);
  o.y = xv.y + bf2f(c0.y) + bf2f(c1.y);
  o.z = xv.z + bf2f(c0.z) + bf2f(c1.z);
  o.w = xv.w + bf2f(c0.w) + bf2f(c1.w);
  reinterpret_cast<float4*>(out)[i] = o;
}

extern "C" void kernel_launch(void* const* d_in, const int* in_sizes, int n_in,
                              void* d_out, int out_size, void* d_ws, size_t ws_size,
                              hipStream_t stream) {
  const float* x  = (const float*)d_in[0];
  const float* rw = (const float*)d_in[1];
  const float* w1 = (const float*)d_in[2];
  const float* b1 = (const float*)d_in[3];
  const float* w2 = (const float*)d_in[4];
  const float* b2 = (const float*)d_in[5];
  float* out = (float*)d_out;
  char* ws = (char*)d_ws;

  const size_t MB = 1u << 20;
  // meta: [0, 8MB)
  int*   counts  = (int*)(ws);
  int*   offsets = (int*)(ws + 64);
  int*   cursors = (int*)(ws + 128);
  int*   tidx    = (int*)(ws + 1 * MB);
  float* twt     = (float*)(ws + 2 * MB);
  int*   ltok    = (int*)(ws + 3 * MB);
  float* lwt     = (float*)(ws + 4 * MB);
  int*   ppos    = (int*)(ws + 5 * MB);
  // overlaid big buffers (lifetimes are disjoint where they overlap):
  ushort_t* xbf     = (ushort_t*)(ws + 8 * MB);     // 32 MB, live cast..gemm1
  ushort_t* contrib = (ushort_t*)(ws + 8 * MB);     // 64 MB, live gemm2..combine (xbf dead)
  ushort_t* Hbuf    = (ushort_t*)(ws + 72 * MB);    // 256 MB, live gemm1..gemm2
  ushort_t* w1t     = (ushort_t*)(ws + 328 * MB);   // 256 MB, live wcvt1..gemm1
  ushort_t* w2t     = (ushort_t*)(ws + 328 * MB);   // 256 MB, live wcvt2..gemm2 (after gemm1)
  const size_t NEED = 584 * MB;
  if (ws_size < NEED) {  // clean, loud failure instead of OOB writes
    hipMemsetAsync(d_out, 0, (size_t)out_size * sizeof(float), stream);
    return;
  }

  hipMemsetAsync(ws, 0, 256, stream);  // counts + cursors
  k_cast<<<dim3((T_TOK * (size_t)DIM / 4) / 256), 256, 0, stream>>>(x, xbf);
  k_router<<<T_TOK, 256, 0, stream>>>(x, rw, tidx, twt, counts);
  k_scan<<<1, 64, 0, stream>>>(counts, offsets);
  k_fill<<<T_TOK / 256, 256, 0, stream>>>(tidx, twt, offsets, cursors, ltok, lwt, ppos);
  // w1: [E][D][F] fp32 -> w1t [E][F][D] bf16
  k_wcvt<<<dim3(FFN / TT, DIM / TT, NE), 256, 0, stream>>>(w1, w1t, DIM, FFN);
  k_gemm1<<<dim3(FFN / BN, T_TOK / BM, NE), 256, 0, stream>>>(xbf, w1t, b1, counts, offsets, ltok, Hbuf);
  // w2: [E][F][D] fp32 -> w2t [E][D][F] bf16  (runs after gemm1; reuses w1t region)
  k_wcvt<<<dim3(DIM / TT, FFN / TT, NE), 256, 0, stream>>>(w2, w2t, FFN, DIM);
  k_gemm2<<<dim3(DIM / BN, T_TOK / BM, NE), 256, 0, stream>>>(Hbuf, w2t, b2, counts, offsets, lwt, contrib);
  k_combine<<<dim3((T_TOK * (size_t)DIM / 4) / 256), 256, 0, stream>>>(x, contrib, ppos, out);
}